// Round 1
// baseline (1909.955 us; speedup 1.0000x reference)
//
#include <hip/hip_runtime.h>
#include <math.h>

// ---------------------------------------------------------------------------
// ConvexGenerator: z -> MLP(2 layers, exact GELU) -> per-class attention over
// padded class memory buffers -> convex combination.
// Key algorithmic cut vs reference: reference computes logits/synth for ALL 8
// classes then selects one; we compute only the sample's own class (8x less).
// Class-grouped GEMMs share the Wa[c]/Xbuf[c] operand across row tiles.
// ---------------------------------------------------------------------------

constexpr int B = 2048, LATENT = 128, C = 8, HID = 1024, D = 512, NMAX = 4096;

// COUNTS = {1024,1536,2048,2560,3072,3584,3840,4096} — compile-time.
__device__ __forceinline__ int class_count(int c) {
    if (c < 6) return 1024 + 512 * c;
    return (c == 6) ? 3840 : 4096;
}

__device__ __forceinline__ float gelu_exact(float x) {
    return 0.5f * x * (1.0f + erff(x * 0.70710678118654752f));
}

__device__ __forceinline__ float waveMax(float v) {
    #pragma unroll
    for (int o = 32; o > 0; o >>= 1) v = fmaxf(v, __shfl_down(v, o));
    return v;
}
__device__ __forceinline__ float waveSum(float v) {
    #pragma unroll
    for (int o = 32; o > 0; o >>= 1) v += __shfl_down(v, o);
    return v;
}

// --- 1) per-class gather lists (order-independent -> atomics are safe) ------
__global__ void k_gather(const int* __restrict__ cid, int* __restrict__ cnt,
                         int* __restrict__ idx) {
    int b = blockIdx.x * 256 + threadIdx.x;
    if (b < B) {
        int c = cid[b];
        int s = atomicAdd(&cnt[c], 1);
        idx[c * B + s] = b;
    }
}

// --- 2) MLP layer: Out = gelu(A[.,K] @ W[K,HID] + bias (+ onehot row)) ------
// 64x64 tile, 256 threads, 4x4 microtile, As transposed (stride 68 keeps
// float4 alignment + spreads staging-write banks).
template <int K>
__global__ __launch_bounds__(256) void k_mlp(const float* __restrict__ A,
                                             const float* __restrict__ W,
                                             const float* __restrict__ bias,
                                             const float* __restrict__ Woh,
                                             const int* __restrict__ cid,
                                             float* __restrict__ Out) {
    __shared__ float As[32][68];
    __shared__ float Bs[32][64];
    const int t = threadIdx.x, tx = t & 15, ty = t >> 4;
    const int row0 = blockIdx.x * 64, col0 = blockIdx.y * 64;
    float acc[4][4] = {};
    for (int k0 = 0; k0 < K; k0 += 32) {
        #pragma unroll
        for (int i = 0; i < 2; ++i) {
            int li = t + i * 256;
            int m = li >> 3, kq = li & 7;
            float4 a = *(const float4*)&A[(size_t)(row0 + m) * K + k0 + kq * 4];
            As[kq * 4 + 0][m] = a.x; As[kq * 4 + 1][m] = a.y;
            As[kq * 4 + 2][m] = a.z; As[kq * 4 + 3][m] = a.w;
        }
        #pragma unroll
        for (int i = 0; i < 2; ++i) {
            int li = t + i * 256;
            int kk = li >> 4, nq = li & 15;
            *(float4*)&Bs[kk][nq * 4] =
                *(const float4*)&W[(size_t)(k0 + kk) * HID + col0 + nq * 4];
        }
        __syncthreads();
        #pragma unroll
        for (int kk = 0; kk < 32; ++kk) {
            float4 a = *(const float4*)&As[kk][ty * 4];
            float4 b = *(const float4*)&Bs[kk][tx * 4];
            float av[4] = {a.x, a.y, a.z, a.w};
            float bv[4] = {b.x, b.y, b.z, b.w};
            #pragma unroll
            for (int i = 0; i < 4; ++i)
                #pragma unroll
                for (int j = 0; j < 4; ++j)
                    acc[i][j] = fmaf(av[i], bv[j], acc[i][j]);
        }
        __syncthreads();
    }
    const int ccol = col0 + tx * 4;
    float4 bv = *(const float4*)&bias[ccol];
    #pragma unroll
    for (int i = 0; i < 4; ++i) {
        int r = row0 + ty * 4 + i;
        float a0 = bv.x, a1 = bv.y, a2 = bv.z, a3 = bv.w;
        if (Woh) {  // one-hot contribution = W1 row (128 + class)
            const float* w = Woh + (size_t)cid[r] * HID + ccol;
            a0 += w[0]; a1 += w[1]; a2 += w[2]; a3 += w[3];
        }
        float4 o;
        o.x = gelu_exact(acc[i][0] + a0);
        o.y = gelu_exact(acc[i][1] + a1);
        o.z = gelu_exact(acc[i][2] + a2);
        o.w = gelu_exact(acc[i][3] + a3);
        *(float4*)&Out[(size_t)r * HID + ccol] = o;
    }
}

// --- 3) grouped logits GEMM: L[g, n] = t[g] @ Wa[c][:, n] + ba[c][n] --------
// 128x64 tile, 256 threads, 8x4 microtile. Rows gathered via idx[c].
__global__ __launch_bounds__(256) void k_logits(const float* __restrict__ T,
                                                const float* __restrict__ Wa,
                                                const float* __restrict__ ba,
                                                const int* __restrict__ cnt,
                                                const int* __restrict__ idxs,
                                                float* __restrict__ L) {
    const int c = blockIdx.y;
    const int count = class_count(c);
    const int n0 = blockIdx.z * 64;
    if (n0 >= count) return;               // count-limited: skip padded tiles
    const int Mc = cnt[c];
    const int row0 = blockIdx.x * 128;
    if (row0 >= Mc) return;
    const int* idxc = idxs + c * B;
    const float* Wc = Wa + (size_t)c * HID * NMAX;

    __shared__ float As[32][132];
    __shared__ float Bs[32][64];
    const int t = threadIdx.x, tx = t & 15, ty = t >> 4;

    int gs[4];
    #pragma unroll
    for (int i = 0; i < 4; ++i) {
        int r = row0 + (t >> 3) + i * 32;
        gs[i] = idxc[min(r, Mc - 1)];
    }
    float acc[8][4] = {};
    for (int k0 = 0; k0 < HID; k0 += 32) {
        #pragma unroll
        for (int i = 0; i < 4; ++i) {
            int m = (t >> 3) + i * 32;
            int kq = t & 7;
            float4 a = *(const float4*)&T[(size_t)gs[i] * HID + k0 + kq * 4];
            As[kq * 4 + 0][m] = a.x; As[kq * 4 + 1][m] = a.y;
            As[kq * 4 + 2][m] = a.z; As[kq * 4 + 3][m] = a.w;
        }
        #pragma unroll
        for (int i = 0; i < 2; ++i) {
            int li = t + i * 256;
            int kk = li >> 4, nq = li & 15;
            *(float4*)&Bs[kk][nq * 4] =
                *(const float4*)&Wc[(size_t)(k0 + kk) * NMAX + n0 + nq * 4];
        }
        __syncthreads();
        #pragma unroll
        for (int kk = 0; kk < 32; ++kk) {
            float4 a0 = *(const float4*)&As[kk][ty * 8];
            float4 a1 = *(const float4*)&As[kk][ty * 8 + 4];
            float4 b = *(const float4*)&Bs[kk][tx * 4];
            float av[8] = {a0.x, a0.y, a0.z, a0.w, a1.x, a1.y, a1.z, a1.w};
            float bv[4] = {b.x, b.y, b.z, b.w};
            #pragma unroll
            for (int i = 0; i < 8; ++i)
                #pragma unroll
                for (int j = 0; j < 4; ++j)
                    acc[i][j] = fmaf(av[i], bv[j], acc[i][j]);
        }
        __syncthreads();
    }
    const int ccol = n0 + tx * 4;
    float4 bav = *(const float4*)&ba[c * NMAX + ccol];
    #pragma unroll
    for (int i = 0; i < 8; ++i) {
        int r = row0 + ty * 8 + i;
        if (r < Mc) {
            int g = idxc[r];
            float4 o;
            o.x = acc[i][0] + bav.x; o.y = acc[i][1] + bav.y;
            o.z = acc[i][2] + bav.z; o.w = acc[i][3] + bav.w;
            *(float4*)&L[(size_t)g * NMAX + ccol] = o;
        }
    }
}

// --- 4) per-row softmax over the first count columns (rest never read) ------
__global__ __launch_bounds__(256) void k_softmax(float* __restrict__ L,
                                                 const int* __restrict__ cid) {
    const int b = blockIdx.x;
    const int n = class_count(cid[b]);
    float* row = L + (size_t)b * NMAX;
    const int t = threadIdx.x;
    float v[16];
    int nv = 0;
    float mx = -INFINITY;
    for (int i = t; i < n; i += 256) {
        float x = row[i];
        v[nv++] = x;
        mx = fmaxf(mx, x);
    }
    __shared__ float red[4], red2[4];
    float wm = waveMax(mx);
    int wid = t >> 6, lid = t & 63;
    if (lid == 0) red[wid] = wm;
    __syncthreads();
    float bmax = fmaxf(fmaxf(red[0], red[1]), fmaxf(red[2], red[3]));
    float s = 0.f;
    #pragma unroll
    for (int j = 0; j < 16; ++j)
        if (j < nv) { v[j] = expf(v[j] - bmax); s += v[j]; }
    float ws_ = waveSum(s);
    if (lid == 0) red2[wid] = ws_;
    __syncthreads();
    float inv = 1.0f / (red2[0] + red2[1] + red2[2] + red2[3]);
    int j = 0;
    for (int i = t; i < n; i += 256) row[i] = v[j++] * inv;
}

// --- 5) grouped synth GEMM: out[g] = alpha[g, :count] @ Xbuf[c][:count] -----
__global__ __launch_bounds__(256) void k_synth(const float* __restrict__ L,
                                               const float* __restrict__ Xbuf,
                                               const int* __restrict__ cnt,
                                               const int* __restrict__ idxs,
                                               float* __restrict__ Out) {
    const int c = blockIdx.y;
    const int count = class_count(c);
    const int Mc = cnt[c];
    const int row0 = blockIdx.x * 128;
    if (row0 >= Mc) return;
    const int n0 = blockIdx.z * 64;
    const int* idxc = idxs + c * B;
    const float* Xc = Xbuf + (size_t)c * NMAX * D;

    __shared__ float As[32][132];
    __shared__ float Bs[32][64];
    const int t = threadIdx.x, tx = t & 15, ty = t >> 4;

    int gs[4];
    #pragma unroll
    for (int i = 0; i < 4; ++i) {
        int r = row0 + (t >> 3) + i * 32;
        gs[i] = idxc[min(r, Mc - 1)];
    }
    float acc[8][4] = {};
    for (int k0 = 0; k0 < count; k0 += 32) {   // K = count (multiple of 256)
        #pragma unroll
        for (int i = 0; i < 4; ++i) {
            int m = (t >> 3) + i * 32;
            int kq = t & 7;
            float4 a = *(const float4*)&L[(size_t)gs[i] * NMAX + k0 + kq * 4];
            As[kq * 4 + 0][m] = a.x; As[kq * 4 + 1][m] = a.y;
            As[kq * 4 + 2][m] = a.z; As[kq * 4 + 3][m] = a.w;
        }
        #pragma unroll
        for (int i = 0; i < 2; ++i) {
            int li = t + i * 256;
            int kk = li >> 4, nq = li & 15;
            *(float4*)&Bs[kk][nq * 4] =
                *(const float4*)&Xc[(size_t)(k0 + kk) * D + n0 + nq * 4];
        }
        __syncthreads();
        #pragma unroll
        for (int kk = 0; kk < 32; ++kk) {
            float4 a0 = *(const float4*)&As[kk][ty * 8];
            float4 a1 = *(const float4*)&As[kk][ty * 8 + 4];
            float4 b = *(const float4*)&Bs[kk][tx * 4];
            float av[8] = {a0.x, a0.y, a0.z, a0.w, a1.x, a1.y, a1.z, a1.w};
            float bv[4] = {b.x, b.y, b.z, b.w};
            #pragma unroll
            for (int i = 0; i < 8; ++i)
                #pragma unroll
                for (int j = 0; j < 4; ++j)
                    acc[i][j] = fmaf(av[i], bv[j], acc[i][j]);
        }
        __syncthreads();
    }
    const int ccol = n0 + tx * 4;
    #pragma unroll
    for (int i = 0; i < 8; ++i) {
        int r = row0 + ty * 8 + i;
        if (r < Mc) {
            int g = idxc[r];
            float4 o = {acc[i][0], acc[i][1], acc[i][2], acc[i][3]};
            *(float4*)&Out[(size_t)g * D + ccol] = o;
        }
    }
}

// ---------------------------------------------------------------------------
extern "C" void kernel_launch(void* const* d_in, const int* in_sizes, int n_in,
                              void* d_out, int out_size, void* d_ws,
                              size_t ws_size, hipStream_t stream) {
    const float* z    = (const float*)d_in[0];
    const int*   cid  = (const int*)d_in[1];
    const float* W1   = (const float*)d_in[2];
    const float* b1   = (const float*)d_in[3];
    const float* W2   = (const float*)d_in[4];
    const float* b2   = (const float*)d_in[5];
    const float* Wa   = (const float*)d_in[6];
    const float* ba   = (const float*)d_in[7];
    const float* Xbuf = (const float*)d_in[8];
    float* out = (float*)d_out;

    // Workspace layout (all offsets 256-aligned); total ~48.1 MB.
    char* ws = (char*)d_ws;
    int*   cnt    = (int*)ws;                       // 256 B (8 used)
    int*   idx    = (int*)(ws + 256);               // 8*2048*4 = 64 KB
    float* h      = (float*)(ws + 65792);           // 8 MB
    float* tbuf   = (float*)(ws + 8454400);         // 8 MB
    float* logits = (float*)(ws + 16843008);        // 32 MB (reused as alpha)

    hipMemsetAsync(cnt, 0, 256, stream);
    k_gather<<<dim3(B / 256), 256, 0, stream>>>(cid, cnt, idx);
    k_mlp<LATENT><<<dim3(B / 64, HID / 64), 256, 0, stream>>>(
        z, W1, b1, W1 + (size_t)LATENT * HID, cid, h);
    k_mlp<HID><<<dim3(B / 64, HID / 64), 256, 0, stream>>>(
        h, W2, b2, nullptr, cid, tbuf);
    k_logits<<<dim3(B / 128, C, NMAX / 64), 256, 0, stream>>>(
        tbuf, Wa, ba, cnt, idx, logits);
    k_softmax<<<dim3(B), 256, 0, stream>>>(logits, cid);
    k_synth<<<dim3(B / 128, C, D / 64), 256, 0, stream>>>(
        logits, Xbuf, cnt, idx, out);
}

// Round 2
// 925.384 us; speedup vs baseline: 2.0640x; 2.0640x over previous
//
#include <hip/hip_runtime.h>
#include <math.h>

// ---------------------------------------------------------------------------
// ConvexGenerator. Round 2: fix the strided-B-operand DRAM pathology.
// rocprof R1: k_logits 1010us, VALUBusy 10%, HBM 2.4% -> latency/page-thrash
// bound on 256B-per-16KB-stride Wa reads. Fix: one-time coalesced repack of
// Wa -> [c][ntile][k][64] (bf16) and Xbuf -> [c][dtile][n][64] (fp32); GEMM
// B-stages become single contiguous 4-8KB reads. k_synth gets split-K +
// atomicAdd (class-7 K=4096 serial tail was ~109us on one block).
// ---------------------------------------------------------------------------

constexpr int B = 2048, LATENT = 128, C = 8, HID = 1024, D = 512, NMAX = 4096;

__device__ __forceinline__ int class_count(int c) {
    if (c < 6) return 1024 + 512 * c;
    return (c == 6) ? 3840 : 4096;
}

__device__ __forceinline__ float gelu_exact(float x) {
    return 0.5f * x * (1.0f + erff(x * 0.70710678118654752f));
}

__device__ __forceinline__ float waveMax(float v) {
    #pragma unroll
    for (int o = 32; o > 0; o >>= 1) v = fmaxf(v, __shfl_down(v, o));
    return v;
}
__device__ __forceinline__ float waveSum(float v) {
    #pragma unroll
    for (int o = 32; o > 0; o >>= 1) v += __shfl_down(v, o);
    return v;
}

__device__ __forceinline__ unsigned short f2bf(float f) {  // RNE
    unsigned int u = __float_as_uint(f);
    return (unsigned short)((u + 0x7fffu + ((u >> 16) & 1u)) >> 16);
}
__device__ __forceinline__ float bf2f_lo(unsigned int u) {
    return __uint_as_float(u << 16);
}
__device__ __forceinline__ float bf2f_hi(unsigned int u) {
    return __uint_as_float(u & 0xffff0000u);
}

// --- 1) per-class gather lists (order-independent -> atomics replay-safe) ---
__global__ void k_gather(const int* __restrict__ cid, int* __restrict__ cnt,
                         int* __restrict__ idx) {
    int b = blockIdx.x * 256 + threadIdx.x;
    if (b < B) {
        int c = cid[b];
        int s = atomicAdd(&cnt[c], 1);
        idx[c * B + s] = b;
    }
}

// --- repack Wa[c][h][n] fp32 -> Wrep[c][n/64][h][64] bf16 (coalesced read) --
__global__ __launch_bounds__(1024) void k_repack_wa(const float* __restrict__ Wa,
                                                    unsigned short* __restrict__ Wrep) {
    const int h = blockIdx.x, c = blockIdx.y, t = threadIdx.x;
    float4 v = *(const float4*)&Wa[((size_t)c * HID + h) * NMAX + 4 * t];
    int ntile = (4 * t) >> 6, col = (4 * t) & 63;
    ushort4 o = {f2bf(v.x), f2bf(v.y), f2bf(v.z), f2bf(v.w)};
    *(ushort4*)&Wrep[(((size_t)c * 64 + ntile) * HID + h) * 64 + col] = o;
}

// --- repack Xbuf[c][n][d] fp32 -> Xrep[c][d/64][n][64] fp32 -----------------
__global__ __launch_bounds__(128) void k_repack_x(const float* __restrict__ Xbuf,
                                                  float* __restrict__ Xrep) {
    const int n = blockIdx.x, c = blockIdx.y, t = threadIdx.x;
    float4 v = *(const float4*)&Xbuf[((size_t)c * NMAX + n) * D + 4 * t];
    int dt = (4 * t) >> 6, col = (4 * t) & 63;
    *(float4*)&Xrep[(((size_t)c * 8 + dt) * NMAX + n) * 64 + col] = v;
}

// --- 2) MLP layer: Out = gelu(A[.,K] @ W[K,HID] + bias (+ onehot row)) ------
template <int K>
__global__ __launch_bounds__(256) void k_mlp(const float* __restrict__ A,
                                             const float* __restrict__ W,
                                             const float* __restrict__ bias,
                                             const float* __restrict__ Woh,
                                             const int* __restrict__ cid,
                                             float* __restrict__ Out) {
    __shared__ float As[32][68];
    __shared__ float Bs[32][64];
    const int t = threadIdx.x, tx = t & 15, ty = t >> 4;
    const int row0 = blockIdx.x * 64, col0 = blockIdx.y * 64;
    float acc[4][4] = {};
    for (int k0 = 0; k0 < K; k0 += 32) {
        #pragma unroll
        for (int i = 0; i < 2; ++i) {
            int li = t + i * 256;
            int m = li >> 3, kq = li & 7;
            float4 a = *(const float4*)&A[(size_t)(row0 + m) * K + k0 + kq * 4];
            As[kq * 4 + 0][m] = a.x; As[kq * 4 + 1][m] = a.y;
            As[kq * 4 + 2][m] = a.z; As[kq * 4 + 3][m] = a.w;
        }
        #pragma unroll
        for (int i = 0; i < 2; ++i) {
            int li = t + i * 256;
            int kk = li >> 4, nq = li & 15;
            *(float4*)&Bs[kk][nq * 4] =
                *(const float4*)&W[(size_t)(k0 + kk) * HID + col0 + nq * 4];
        }
        __syncthreads();
        #pragma unroll
        for (int kk = 0; kk < 32; ++kk) {
            float4 a = *(const float4*)&As[kk][ty * 4];
            float4 b = *(const float4*)&Bs[kk][tx * 4];
            float av[4] = {a.x, a.y, a.z, a.w};
            float bv[4] = {b.x, b.y, b.z, b.w};
            #pragma unroll
            for (int i = 0; i < 4; ++i)
                #pragma unroll
                for (int j = 0; j < 4; ++j)
                    acc[i][j] = fmaf(av[i], bv[j], acc[i][j]);
        }
        __syncthreads();
    }
    const int ccol = col0 + tx * 4;
    float4 bv = *(const float4*)&bias[ccol];
    #pragma unroll
    for (int i = 0; i < 4; ++i) {
        int r = row0 + ty * 4 + i;
        float a0 = bv.x, a1 = bv.y, a2 = bv.z, a3 = bv.w;
        if (Woh) {
            const float* w = Woh + (size_t)cid[r] * HID + ccol;
            a0 += w[0]; a1 += w[1]; a2 += w[2]; a3 += w[3];
        }
        float4 o;
        o.x = gelu_exact(acc[i][0] + a0);
        o.y = gelu_exact(acc[i][1] + a1);
        o.z = gelu_exact(acc[i][2] + a2);
        o.w = gelu_exact(acc[i][3] + a3);
        *(float4*)&Out[(size_t)r * HID + ccol] = o;
    }
}

// --- 3) grouped logits GEMM vs repacked bf16 Wa -----------------------------
// B-stage: one contiguous 4KB chunk per k-tile (Wrep[c][ntile][k0..k0+31][64]).
__global__ __launch_bounds__(256) void k_logits2(const float* __restrict__ T,
                                                 const unsigned short* __restrict__ Wrep,
                                                 const float* __restrict__ ba,
                                                 const int* __restrict__ cnt,
                                                 const int* __restrict__ idxs,
                                                 float* __restrict__ L) {
    const int c = blockIdx.y;
    const int count = class_count(c);
    const int n0 = blockIdx.z * 64;
    if (n0 >= count) return;
    const int Mc = cnt[c];
    const int row0 = blockIdx.x * 128;
    if (row0 >= Mc) return;
    const int* idxc = idxs + c * B;

    __shared__ float As[32][132];
    __shared__ float Bs[32][64];
    const int t = threadIdx.x, tx = t & 15, ty = t >> 4;

    int gs[4];
    #pragma unroll
    for (int i = 0; i < 4; ++i) {
        int r = row0 + (t >> 3) + i * 32;
        gs[i] = idxc[min(r, Mc - 1)];
    }
    const size_t wbase = ((size_t)c * 64 + (n0 >> 6)) * HID * 64;
    float acc[8][4] = {};
    for (int k0 = 0; k0 < HID; k0 += 32) {
        #pragma unroll
        for (int i = 0; i < 4; ++i) {
            int m = (t >> 3) + i * 32;
            int kq = t & 7;
            float4 a = *(const float4*)&T[(size_t)gs[i] * HID + k0 + kq * 4];
            As[kq * 4 + 0][m] = a.x; As[kq * 4 + 1][m] = a.y;
            As[kq * 4 + 2][m] = a.z; As[kq * 4 + 3][m] = a.w;
        }
        {   // 32x64 bf16 tile = 4KB contiguous; thread t covers elems t*8..t*8+7
            uint4 u = *(const uint4*)&Wrep[wbase + (size_t)k0 * 64 + t * 8];
            float* bsf = &((float*)Bs)[t * 8];
            float4 w0 = {bf2f_lo(u.x), bf2f_hi(u.x), bf2f_lo(u.y), bf2f_hi(u.y)};
            float4 w1 = {bf2f_lo(u.z), bf2f_hi(u.z), bf2f_lo(u.w), bf2f_hi(u.w)};
            *(float4*)bsf = w0;
            *(float4*)(bsf + 4) = w1;
        }
        __syncthreads();
        #pragma unroll
        for (int kk = 0; kk < 32; ++kk) {
            float4 a0 = *(const float4*)&As[kk][ty * 8];
            float4 a1 = *(const float4*)&As[kk][ty * 8 + 4];
            float4 b = *(const float4*)&Bs[kk][tx * 4];
            float av[8] = {a0.x, a0.y, a0.z, a0.w, a1.x, a1.y, a1.z, a1.w};
            float bv[4] = {b.x, b.y, b.z, b.w};
            #pragma unroll
            for (int i = 0; i < 8; ++i)
                #pragma unroll
                for (int j = 0; j < 4; ++j)
                    acc[i][j] = fmaf(av[i], bv[j], acc[i][j]);
        }
        __syncthreads();
    }
    const int ccol = n0 + tx * 4;
    float4 bav = *(const float4*)&ba[c * NMAX + ccol];
    #pragma unroll
    for (int i = 0; i < 8; ++i) {
        int r = row0 + ty * 8 + i;
        if (r < Mc) {
            int g = idxc[r];
            float4 o;
            o.x = acc[i][0] + bav.x; o.y = acc[i][1] + bav.y;
            o.z = acc[i][2] + bav.z; o.w = acc[i][3] + bav.w;
            *(float4*)&L[(size_t)g * NMAX + ccol] = o;
        }
    }
}

// --- 4) per-row softmax over first count columns ----------------------------
__global__ __launch_bounds__(256) void k_softmax(float* __restrict__ L,
                                                 const int* __restrict__ cid) {
    const int b = blockIdx.x;
    const int n = class_count(cid[b]);
    float* row = L + (size_t)b * NMAX;
    const int t = threadIdx.x;
    float v[16];
    int nv = 0;
    float mx = -INFINITY;
    for (int i = t; i < n; i += 256) {
        float x = row[i];
        v[nv++] = x;
        mx = fmaxf(mx, x);
    }
    __shared__ float red[4], red2[4];
    float wm = waveMax(mx);
    int wid = t >> 6, lid = t & 63;
    if (lid == 0) red[wid] = wm;
    __syncthreads();
    float bmax = fmaxf(fmaxf(red[0], red[1]), fmaxf(red[2], red[3]));
    float s = 0.f;
    #pragma unroll
    for (int j = 0; j < 16; ++j)
        if (j < nv) { v[j] = expf(v[j] - bmax); s += v[j]; }
    float ws_ = waveSum(s);
    if (lid == 0) red2[wid] = ws_;
    __syncthreads();
    float inv = 1.0f / (red2[0] + red2[1] + red2[2] + red2[3]);
    int j = 0;
    for (int i = t; i < n; i += 256) row[i] = v[j++] * inv;
}

// --- 5) grouped synth GEMM vs repacked Xbuf, split-K + atomicAdd ------------
// z packs (dtile in [0,8), kchunk in [0,4)); each kchunk covers 1024 k.
__global__ __launch_bounds__(256) void k_synth2(const float* __restrict__ L,
                                                const float* __restrict__ Xrep,
                                                const int* __restrict__ cnt,
                                                const int* __restrict__ idxs,
                                                float* __restrict__ Out) {
    const int c = blockIdx.y;
    const int count = class_count(c);
    const int dtile = blockIdx.z >> 2, kci = blockIdx.z & 3;
    const int kc0 = kci * 1024;
    if (kc0 >= count) return;
    const int kc1 = min(kc0 + 1024, count);
    const int Mc = cnt[c];
    const int row0 = blockIdx.x * 128;
    if (row0 >= Mc) return;
    const int* idxc = idxs + c * B;

    __shared__ float As[32][132];
    __shared__ float Bs[32][64];
    const int t = threadIdx.x, tx = t & 15, ty = t >> 4;

    int gs[4];
    #pragma unroll
    for (int i = 0; i < 4; ++i) {
        int r = row0 + (t >> 3) + i * 32;
        gs[i] = idxc[min(r, Mc - 1)];
    }
    const size_t xbase = ((size_t)c * 8 + dtile) * NMAX * 64;
    float acc[8][4] = {};
    for (int k0 = kc0; k0 < kc1; k0 += 32) {
        #pragma unroll
        for (int i = 0; i < 4; ++i) {
            int m = (t >> 3) + i * 32;
            int kq = t & 7;
            float4 a = *(const float4*)&L[(size_t)gs[i] * NMAX + k0 + kq * 4];
            As[kq * 4 + 0][m] = a.x; As[kq * 4 + 1][m] = a.y;
            As[kq * 4 + 2][m] = a.z; As[kq * 4 + 3][m] = a.w;
        }
        {   // 32x64 fp32 tile = 8KB contiguous
            const float4* src = (const float4*)&Xrep[xbase + (size_t)k0 * 64 + t * 8];
            float* bsf = &((float*)Bs)[t * 8];
            *(float4*)bsf = src[0];
            *(float4*)(bsf + 4) = src[1];
        }
        __syncthreads();
        #pragma unroll
        for (int kk = 0; kk < 32; ++kk) {
            float4 a0 = *(const float4*)&As[kk][ty * 8];
            float4 a1 = *(const float4*)&As[kk][ty * 8 + 4];
            float4 b = *(const float4*)&Bs[kk][tx * 4];
            float av[8] = {a0.x, a0.y, a0.z, a0.w, a1.x, a1.y, a1.z, a1.w};
            float bv[4] = {b.x, b.y, b.z, b.w};
            #pragma unroll
            for (int i = 0; i < 8; ++i)
                #pragma unroll
                for (int j = 0; j < 4; ++j)
                    acc[i][j] = fmaf(av[i], bv[j], acc[i][j]);
        }
        __syncthreads();
    }
    const int ccol = dtile * 64 + tx * 4;
    #pragma unroll
    for (int i = 0; i < 8; ++i) {
        int r = row0 + ty * 8 + i;
        if (r < Mc) {
            int g = idxc[r];
            float* o = &Out[(size_t)g * D + ccol];
            atomicAdd(o + 0, acc[i][0]);
            atomicAdd(o + 1, acc[i][1]);
            atomicAdd(o + 2, acc[i][2]);
            atomicAdd(o + 3, acc[i][3]);
        }
    }
}

// --- fallback (R1) kernels, used only if ws_size too small ------------------
__global__ __launch_bounds__(256) void k_logits_fb(const float* __restrict__ T,
                                                   const float* __restrict__ Wa,
                                                   const float* __restrict__ ba,
                                                   const int* __restrict__ cnt,
                                                   const int* __restrict__ idxs,
                                                   float* __restrict__ L) {
    const int c = blockIdx.y;
    const int count = class_count(c);
    const int n0 = blockIdx.z * 64;
    if (n0 >= count) return;
    const int Mc = cnt[c];
    const int row0 = blockIdx.x * 128;
    if (row0 >= Mc) return;
    const int* idxc = idxs + c * B;
    const float* Wc = Wa + (size_t)c * HID * NMAX;
    __shared__ float As[32][132];
    __shared__ float Bs[32][64];
    const int t = threadIdx.x, tx = t & 15, ty = t >> 4;
    int gs[4];
    #pragma unroll
    for (int i = 0; i < 4; ++i) {
        int r = row0 + (t >> 3) + i * 32;
        gs[i] = idxc[min(r, Mc - 1)];
    }
    float acc[8][4] = {};
    for (int k0 = 0; k0 < HID; k0 += 32) {
        #pragma unroll
        for (int i = 0; i < 4; ++i) {
            int m = (t >> 3) + i * 32;
            int kq = t & 7;
            float4 a = *(const float4*)&T[(size_t)gs[i] * HID + k0 + kq * 4];
            As[kq * 4 + 0][m] = a.x; As[kq * 4 + 1][m] = a.y;
            As[kq * 4 + 2][m] = a.z; As[kq * 4 + 3][m] = a.w;
        }
        #pragma unroll
        for (int i = 0; i < 2; ++i) {
            int li = t + i * 256;
            int kk = li >> 4, nq = li & 15;
            *(float4*)&Bs[kk][nq * 4] =
                *(const float4*)&Wc[(size_t)(k0 + kk) * NMAX + n0 + nq * 4];
        }
        __syncthreads();
        #pragma unroll
        for (int kk = 0; kk < 32; ++kk) {
            float4 a0 = *(const float4*)&As[kk][ty * 8];
            float4 a1 = *(const float4*)&As[kk][ty * 8 + 4];
            float4 b = *(const float4*)&Bs[kk][tx * 4];
            float av[8] = {a0.x, a0.y, a0.z, a0.w, a1.x, a1.y, a1.z, a1.w};
            float bv[4] = {b.x, b.y, b.z, b.w};
            #pragma unroll
            for (int i = 0; i < 8; ++i)
                #pragma unroll
                for (int j = 0; j < 4; ++j)
                    acc[i][j] = fmaf(av[i], bv[j], acc[i][j]);
        }
        __syncthreads();
    }
    const int ccol = n0 + tx * 4;
    float4 bav = *(const float4*)&ba[c * NMAX + ccol];
    #pragma unroll
    for (int i = 0; i < 8; ++i) {
        int r = row0 + ty * 8 + i;
        if (r < Mc) {
            int g = idxc[r];
            float4 o;
            o.x = acc[i][0] + bav.x; o.y = acc[i][1] + bav.y;
            o.z = acc[i][2] + bav.z; o.w = acc[i][3] + bav.w;
            *(float4*)&L[(size_t)g * NMAX + ccol] = o;
        }
    }
}

__global__ __launch_bounds__(256) void k_synth_fb(const float* __restrict__ L,
                                                  const float* __restrict__ Xbuf,
                                                  const int* __restrict__ cnt,
                                                  const int* __restrict__ idxs,
                                                  float* __restrict__ Out) {
    const int c = blockIdx.y;
    const int count = class_count(c);
    const int Mc = cnt[c];
    const int row0 = blockIdx.x * 128;
    if (row0 >= Mc) return;
    const int n0 = blockIdx.z * 64;
    const int* idxc = idxs + c * B;
    const float* Xc = Xbuf + (size_t)c * NMAX * D;
    __shared__ float As[32][132];
    __shared__ float Bs[32][64];
    const int t = threadIdx.x, tx = t & 15, ty = t >> 4;
    int gs[4];
    #pragma unroll
    for (int i = 0; i < 4; ++i) {
        int r = row0 + (t >> 3) + i * 32;
        gs[i] = idxc[min(r, Mc - 1)];
    }
    float acc[8][4] = {};
    for (int k0 = 0; k0 < count; k0 += 32) {
        #pragma unroll
        for (int i = 0; i < 4; ++i) {
            int m = (t >> 3) + i * 32;
            int kq = t & 7;
            float4 a = *(const float4*)&L[(size_t)gs[i] * NMAX + k0 + kq * 4];
            As[kq * 4 + 0][m] = a.x; As[kq * 4 + 1][m] = a.y;
            As[kq * 4 + 2][m] = a.z; As[kq * 4 + 3][m] = a.w;
        }
        #pragma unroll
        for (int i = 0; i < 2; ++i) {
            int li = t + i * 256;
            int kk = li >> 4, nq = li & 15;
            *(float4*)&Bs[kk][nq * 4] =
                *(const float4*)&Xc[(size_t)(k0 + kk) * D + n0 + nq * 4];
        }
        __syncthreads();
        #pragma unroll
        for (int kk = 0; kk < 32; ++kk) {
            float4 a0 = *(const float4*)&As[kk][ty * 8];
            float4 a1 = *(const float4*)&As[kk][ty * 8 + 4];
            float4 b = *(const float4*)&Bs[kk][tx * 4];
            float av[8] = {a0.x, a0.y, a0.z, a0.w, a1.x, a1.y, a1.z, a1.w};
            float bv[4] = {b.x, b.y, b.z, b.w};
            #pragma unroll
            for (int i = 0; i < 8; ++i)
                #pragma unroll
                for (int j = 0; j < 4; ++j)
                    acc[i][j] = fmaf(av[i], bv[j], acc[i][j]);
        }
        __syncthreads();
    }
    const int ccol = n0 + tx * 4;
    #pragma unroll
    for (int i = 0; i < 8; ++i) {
        int r = row0 + ty * 8 + i;
        if (r < Mc) {
            int g = idxc[r];
            float4 o = {acc[i][0], acc[i][1], acc[i][2], acc[i][3]};
            *(float4*)&Out[(size_t)g * D + ccol] = o;
        }
    }
}

// ---------------------------------------------------------------------------
extern "C" void kernel_launch(void* const* d_in, const int* in_sizes, int n_in,
                              void* d_out, int out_size, void* d_ws,
                              size_t ws_size, hipStream_t stream) {
    const float* z    = (const float*)d_in[0];
    const int*   cid  = (const int*)d_in[1];
    const float* W1   = (const float*)d_in[2];
    const float* b1   = (const float*)d_in[3];
    const float* W2   = (const float*)d_in[4];
    const float* b2   = (const float*)d_in[5];
    const float* Wa   = (const float*)d_in[6];
    const float* ba   = (const float*)d_in[7];
    const float* Xbuf = (const float*)d_in[8];
    float* out = (float*)d_out;

    // Workspace layout (bytes):
    char* ws = (char*)d_ws;
    int*   cnt    = (int*)ws;                        // 256 B
    int*   idx    = (int*)(ws + 256);                // 64 KB
    float* h      = (float*)(ws + 65792);            // 8 MB
    float* tbuf   = (float*)(ws + 8454400);          // 8 MB
    float* logits = (float*)(ws + 16843008);         // 32 MB
    unsigned short* Wrep = (unsigned short*)(ws + 50397440);  // 64 MB bf16
    float* Xrep   = (float*)(ws + 117506304);        // 64 MB fp32
    const size_t NEED = 184615168;

    const bool fast = ws_size >= NEED;

    hipMemsetAsync(cnt, 0, 256, stream);
    k_gather<<<dim3(B / 256), 256, 0, stream>>>(cid, cnt, idx);
    if (fast) {
        k_repack_wa<<<dim3(HID, C), 1024, 0, stream>>>(Wa, Wrep);
        k_repack_x<<<dim3(NMAX, C), 128, 0, stream>>>(Xbuf, Xrep);
    }
    k_mlp<LATENT><<<dim3(B / 64, HID / 64), 256, 0, stream>>>(
        z, W1, b1, W1 + (size_t)LATENT * HID, cid, h);
    k_mlp<HID><<<dim3(B / 64, HID / 64), 256, 0, stream>>>(
        h, W2, b2, nullptr, cid, tbuf);
    if (fast) {
        k_logits2<<<dim3(4, C, NMAX / 64), 256, 0, stream>>>(
            tbuf, Wrep, ba, cnt, idx, logits);
        k_softmax<<<dim3(B), 256, 0, stream>>>(logits, cid);
        hipMemsetAsync(out, 0, (size_t)B * D * 4, stream);
        k_synth2<<<dim3(4, C, 32), 256, 0, stream>>>(
            logits, Xrep, cnt, idx, out);
    } else {
        k_logits_fb<<<dim3(B / 128, C, NMAX / 64), 256, 0, stream>>>(
            tbuf, Wa, ba, cnt, idx, logits);
        k_softmax<<<dim3(B), 256, 0, stream>>>(logits, cid);
        k_synth_fb<<<dim3(B / 128, C, D / 64), 256, 0, stream>>>(
            logits, Xbuf, cnt, idx, out);
    }
}

// Round 3
// 612.023 us; speedup vs baseline: 3.1207x; 1.5120x over previous
//
#include <hip/hip_runtime.h>
#include <math.h>

// ---------------------------------------------------------------------------
// ConvexGenerator. Round 3: move the three big GEMMs (MLP2, logits, synth)
// onto the matrix cores (mfma_f32_16x16x32_bf16). R2 showed the fp32 VALU
// path capped at ~28 TF effective (VALUBusy 26%, occupancy 15%); total GEMM
// work is 22 GF -> MFMA pipe. B operands are repacked once per launch into
// MFMA B-fragment order (lane-contiguous 1KB frags) so GEMM B-loads are raw
// coalesced uint4 global->VGPR; A tiles stage via LDS (bf16, stride-40 rows).
// Frag layouts (HW-verified, guide §3): A[m=lane&15][k=q*8+j],
// B[k=q*8+j][n=lane&15], C/D col=lane&15 row=q*4+reg.
// ---------------------------------------------------------------------------

constexpr int B = 2048, LATENT = 128, C = 8, HID = 1024, D = 512, NMAX = 4096;

typedef __attribute__((ext_vector_type(8))) short bf16x8;
typedef __attribute__((ext_vector_type(4))) float f32x4;

__device__ __forceinline__ int class_count(int c) {
    if (c < 6) return 1024 + 512 * c;
    return (c == 6) ? 3840 : 4096;
}

__device__ __forceinline__ float gelu_exact(float x) {
    return 0.5f * x * (1.0f + erff(x * 0.70710678118654752f));
}

__device__ __forceinline__ unsigned short f2bf(float f) {  // RNE
    unsigned int u = __float_as_uint(f);
    return (unsigned short)((u + 0x7fffu + ((u >> 16) & 1u)) >> 16);
}

__device__ __forceinline__ float waveMax(float v) {
    #pragma unroll
    for (int o = 32; o > 0; o >>= 1) v = fmaxf(v, __shfl_down(v, o));
    return v;
}
__device__ __forceinline__ float waveSum(float v) {
    #pragma unroll
    for (int o = 32; o > 0; o >>= 1) v += __shfl_down(v, o);
    return v;
}

// --- 1) per-class gather lists (order-independent -> atomics replay-safe) ---
__global__ void k_gather(const int* __restrict__ cid, int* __restrict__ cnt,
                         int* __restrict__ idx) {
    int b = blockIdx.x * 256 + threadIdx.x;
    if (b < B) {
        int c = cid[b];
        int s = atomicAdd(&cnt[c], 1);
        idx[c * B + s] = b;
    }
}

// --- fp32 -> bf16 bulk convert (for z) --------------------------------------
__global__ void k_f2bf(const float* __restrict__ src,
                       unsigned short* __restrict__ dst, int n4) {
    int i = blockIdx.x * 256 + threadIdx.x;
    if (i < n4) {
        float4 v = *(const float4*)&src[(size_t)i * 4];
        ushort4 o = {f2bf(v.x), f2bf(v.y), f2bf(v.z), f2bf(v.w)};
        *(ushort4*)&dst[(size_t)i * 4] = o;
    }
}

// --- generic repack: src [R][Cc] fp32 -> bf16 MFMA B-frags ------------------
// dst frag (ctile, rblk): 64 lanes x 8 elems; lane=(q*16+n), elem j =
// src[rblk*32 + q*8 + j][ctile*16 + n]. Frag index = (ctile*(R/32)+rblk)*512.
// limitMode: 1 = skip col tiles >= class_count (Wa), 2 = skip row blocks (Xbuf).
__global__ __launch_bounds__(256) void k_repack_frag(
    const float* __restrict__ src, unsigned short* __restrict__ dst,
    int R, int Cc, size_t srcStride, size_t dstStride, int limitMode) {
    const int cls = blockIdx.z;
    const int rb = blockIdx.x;            // 32 source rows
    const int c0 = blockIdx.y * 256;      // 256 source cols
    if (limitMode == 1 && c0 >= class_count(cls)) return;
    if (limitMode == 2 && rb * 32 >= class_count(cls)) return;
    src += (size_t)cls * srcStride;
    dst += (size_t)cls * dstStride;
    __shared__ float T[32][257];
    const int t = threadIdx.x;
    #pragma unroll
    for (int i = 0; i < 8; ++i) {         // load 32 x 256 fp32, coalesced
        int r = i * 4 + (t >> 6);
        int cc = (t & 63) * 4;
        float4 v = *(const float4*)&src[(size_t)(rb * 32 + r) * Cc + c0 + cc];
        T[r][cc] = v.x; T[r][cc + 1] = v.y; T[r][cc + 2] = v.z; T[r][cc + 3] = v.w;
    }
    __syncthreads();
    const int RB = R >> 5;
    #pragma unroll
    for (int i = 0; i < 4; ++i) {         // write 16 frags, coalesced 16B/lane
        int ct = i * 4 + (t >> 6);
        int lane = t & 63;
        int n = lane & 15, q = lane >> 4;
        unsigned short tmp[8];
        #pragma unroll
        for (int j = 0; j < 8; ++j) tmp[j] = f2bf(T[q * 8 + j][ct * 16 + n]);
        *(uint4*)&dst[(((size_t)(c0 / 16 + ct)) * RB + rb) * 512 + lane * 8] =
            *(const uint4*)tmp;
    }
}

// --- MLP layer via MFMA: Out = gelu(A @ W + bias (+ onehot)) as bf16 --------
// 128x64 tile, 4 waves; wave w owns rows [w*32, w*32+32).
__global__ __launch_bounds__(256) void k_mlp_mfma(
    const unsigned short* __restrict__ A,    // [M][K] bf16
    const unsigned short* __restrict__ Bf,   // B frags, KB = K/32
    const float* __restrict__ bias,
    const float* __restrict__ Woh,           // W1 + 128*HID, or null
    const int* __restrict__ cid,
    unsigned short* __restrict__ Out,        // [M][HID] bf16
    int K) {
    const int row0 = blockIdx.x * 128, col0 = blockIdx.y * 64;
    const int KB = K >> 5;
    const int t = threadIdx.x, wave = t >> 6, lane = t & 63;
    const int ln = lane & 15, lq = lane >> 4;
    __shared__ __align__(16) unsigned short As[128 * 40];
    f32x4 acc[2][4] = {};
    for (int k0 = 0; k0 < K; k0 += 32) {
        #pragma unroll
        for (int i = 0; i < 2; ++i) {
            int idx = t + i * 256;
            int r = idx >> 2, ch = idx & 3;
            *(uint4*)&As[r * 40 + ch * 8] =
                *(const uint4*)&A[(size_t)(row0 + r) * K + k0 + ch * 8];
        }
        __syncthreads();
        const int kb = k0 >> 5;
        bf16x8 bfr[4];
        #pragma unroll
        for (int f = 0; f < 4; ++f)
            bfr[f] = *(const bf16x8*)&Bf[((size_t)((col0 >> 4) + f) * KB + kb) * 512 + lane * 8];
        #pragma unroll
        for (int h = 0; h < 2; ++h) {
            bf16x8 af = *(const bf16x8*)&As[(wave * 32 + h * 16 + ln) * 40 + lq * 8];
            #pragma unroll
            for (int f = 0; f < 4; ++f)
                acc[h][f] = __builtin_amdgcn_mfma_f32_16x16x32_bf16(af, bfr[f], acc[h][f], 0, 0, 0);
        }
        __syncthreads();
    }
    #pragma unroll
    for (int h = 0; h < 2; ++h) {
        #pragma unroll
        for (int reg = 0; reg < 4; ++reg) {
            int r = row0 + wave * 32 + h * 16 + lq * 4 + reg;
            const float* woh = Woh ? &Woh[(size_t)cid[r] * HID] : nullptr;
            #pragma unroll
            for (int f = 0; f < 4; ++f) {
                int col = col0 + f * 16 + ln;
                float v = acc[h][f][reg] + bias[col];
                if (woh) v += woh[col];
                Out[(size_t)r * HID + col] = f2bf(gelu_exact(v));
            }
        }
    }
}

// --- grouped logits GEMM via MFMA: L[g, n0..n0+63] = t[g] @ Wa[c] + ba ------
__global__ __launch_bounds__(256) void k_logits_mfma(
    const unsigned short* __restrict__ T,    // [B][HID] bf16
    const unsigned short* __restrict__ Wf,   // per-class frags
    const float* __restrict__ ba,
    const int* __restrict__ cnt, const int* __restrict__ idxs,
    float* __restrict__ L) {
    const int c = blockIdx.y;
    const int count = class_count(c);
    const int n0 = blockIdx.z * 64;
    if (n0 >= count) return;
    const int Mc = cnt[c];
    const int row0 = blockIdx.x * 128;
    if (row0 >= Mc) return;
    const int* idxc = idxs + c * B;
    const unsigned short* Wfc = Wf + (size_t)c * 4194304;   // 256*32*512
    const int t = threadIdx.x, wave = t >> 6, lane = t & 63;
    const int ln = lane & 15, lq = lane >> 4;
    __shared__ __align__(16) unsigned short As[128 * 40];
    const int g0 = idxc[min(row0 + (t >> 2), Mc - 1)];
    const int g1 = idxc[min(row0 + (t >> 2) + 64, Mc - 1)];
    f32x4 acc[2][4] = {};
    for (int k0 = 0; k0 < HID; k0 += 32) {
        {
            int r = t >> 2, ch = t & 3;
            *(uint4*)&As[r * 40 + ch * 8] =
                *(const uint4*)&T[(size_t)g0 * HID + k0 + ch * 8];
            *(uint4*)&As[(r + 64) * 40 + ch * 8] =
                *(const uint4*)&T[(size_t)g1 * HID + k0 + ch * 8];
        }
        __syncthreads();
        const int kb = k0 >> 5;
        bf16x8 bfr[4];
        #pragma unroll
        for (int f = 0; f < 4; ++f)
            bfr[f] = *(const bf16x8*)&Wfc[((size_t)((n0 >> 4) + f) * 32 + kb) * 512 + lane * 8];
        #pragma unroll
        for (int h = 0; h < 2; ++h) {
            bf16x8 af = *(const bf16x8*)&As[(wave * 32 + h * 16 + ln) * 40 + lq * 8];
            #pragma unroll
            for (int f = 0; f < 4; ++f)
                acc[h][f] = __builtin_amdgcn_mfma_f32_16x16x32_bf16(af, bfr[f], acc[h][f], 0, 0, 0);
        }
        __syncthreads();
    }
    #pragma unroll
    for (int h = 0; h < 2; ++h) {
        #pragma unroll
        for (int reg = 0; reg < 4; ++reg) {
            int r = row0 + wave * 32 + h * 16 + lq * 4 + reg;
            if (r < Mc) {
                int g = idxc[r];
                #pragma unroll
                for (int f = 0; f < 4; ++f) {
                    int col = n0 + f * 16 + ln;
                    L[(size_t)g * NMAX + col] = acc[h][f][reg] + ba[c * NMAX + col];
                }
            }
        }
    }
}

// --- softmax over first count cols; writes bf16 alpha -----------------------
__global__ __launch_bounds__(256) void k_softmax(const float* __restrict__ L,
                                                 unsigned short* __restrict__ Aout,
                                                 const int* __restrict__ cid) {
    const int b = blockIdx.x;
    const int n = class_count(cid[b]);
    const float* row = L + (size_t)b * NMAX;
    unsigned short* orow = Aout + (size_t)b * NMAX;
    const int t = threadIdx.x;
    float v[16];
    int nv = 0;
    float mx = -INFINITY;
    for (int i = t; i < n; i += 256) {
        float x = row[i];
        v[nv++] = x;
        mx = fmaxf(mx, x);
    }
    __shared__ float red[4], red2[4];
    float wm = waveMax(mx);
    int wid = t >> 6, lid = t & 63;
    if (lid == 0) red[wid] = wm;
    __syncthreads();
    float bmax = fmaxf(fmaxf(red[0], red[1]), fmaxf(red[2], red[3]));
    float s = 0.f;
    #pragma unroll
    for (int j = 0; j < 16; ++j)
        if (j < nv) { v[j] = expf(v[j] - bmax); s += v[j]; }
    float ws_ = waveSum(s);
    if (lid == 0) red2[wid] = ws_;
    __syncthreads();
    float inv = 1.0f / (red2[0] + red2[1] + red2[2] + red2[3]);
    int j = 0;
    for (int i = t; i < n; i += 256) orow[i] = f2bf(v[j++] * inv);
}

// --- grouped synth GEMM via MFMA, split-K(1024) + atomicAdd -----------------
// blockIdx.z = dtile*4 + kchunk; dtile covers 64 of D, kchunk covers 1024 of n.
__global__ __launch_bounds__(256) void k_synth_mfma(
    const unsigned short* __restrict__ Al,   // alpha [B][NMAX] bf16
    const unsigned short* __restrict__ Xf,   // per-class frags
    const int* __restrict__ cnt, const int* __restrict__ idxs,
    float* __restrict__ Out) {
    const int c = blockIdx.y;
    const int count = class_count(c);
    const int dtile = blockIdx.z >> 2, kci = blockIdx.z & 3;
    const int kc0 = kci * 1024;
    if (kc0 >= count) return;
    const int kc1 = min(kc0 + 1024, count);
    const int Mc = cnt[c];
    const int row0 = blockIdx.x * 128;
    if (row0 >= Mc) return;
    const int* idxc = idxs + c * B;
    const unsigned short* Xfc = Xf + (size_t)c * 2097152;   // 32*128*512
    const int d0 = dtile * 64;
    const int t = threadIdx.x, wave = t >> 6, lane = t & 63;
    const int ln = lane & 15, lq = lane >> 4;
    __shared__ __align__(16) unsigned short As[128 * 40];
    const int g0 = idxc[min(row0 + (t >> 2), Mc - 1)];
    const int g1 = idxc[min(row0 + (t >> 2) + 64, Mc - 1)];
    f32x4 acc[2][4] = {};
    for (int k0 = kc0; k0 < kc1; k0 += 32) {
        {
            int r = t >> 2, ch = t & 3;
            *(uint4*)&As[r * 40 + ch * 8] =
                *(const uint4*)&Al[(size_t)g0 * NMAX + k0 + ch * 8];
            *(uint4*)&As[(r + 64) * 40 + ch * 8] =
                *(const uint4*)&Al[(size_t)g1 * NMAX + k0 + ch * 8];
        }
        __syncthreads();
        const int kb = k0 >> 5;                 // 0..127 within class
        bf16x8 bfr[4];
        #pragma unroll
        for (int f = 0; f < 4; ++f)
            bfr[f] = *(const bf16x8*)&Xfc[((size_t)((d0 >> 4) + f) * 128 + kb) * 512 + lane * 8];
        #pragma unroll
        for (int h = 0; h < 2; ++h) {
            bf16x8 af = *(const bf16x8*)&As[(wave * 32 + h * 16 + ln) * 40 + lq * 8];
            #pragma unroll
            for (int f = 0; f < 4; ++f)
                acc[h][f] = __builtin_amdgcn_mfma_f32_16x16x32_bf16(af, bfr[f], acc[h][f], 0, 0, 0);
        }
        __syncthreads();
    }
    #pragma unroll
    for (int h = 0; h < 2; ++h) {
        #pragma unroll
        for (int reg = 0; reg < 4; ++reg) {
            int r = row0 + wave * 32 + h * 16 + lq * 4 + reg;
            if (r < Mc) {
                int g = idxc[r];
                #pragma unroll
                for (int f = 0; f < 4; ++f)
                    atomicAdd(&Out[(size_t)g * D + d0 + f * 16 + ln], acc[h][f][reg]);
            }
        }
    }
}

// ---------------------------------------------------------------------------
extern "C" void kernel_launch(void* const* d_in, const int* in_sizes, int n_in,
                              void* d_out, int out_size, void* d_ws,
                              size_t ws_size, hipStream_t stream) {
    const float* z    = (const float*)d_in[0];
    const int*   cid  = (const int*)d_in[1];
    const float* W1   = (const float*)d_in[2];
    const float* b1   = (const float*)d_in[3];
    const float* W2   = (const float*)d_in[4];
    const float* b2   = (const float*)d_in[5];
    const float* Wa   = (const float*)d_in[6];
    const float* ba   = (const float*)d_in[7];
    const float* Xbuf = (const float*)d_in[8];
    float* out = (float*)d_out;

    // Workspace layout (bytes, all 256-aligned); total ~162.4 MB.
    char* ws = (char*)d_ws;
    int*            cnt   = (int*)ws;                           // 256
    int*            idx   = (int*)(ws + 256);                   // 64 KB
    unsigned short* zbf   = (unsigned short*)(ws + 65792);      // 512 KB
    unsigned short* h     = (unsigned short*)(ws + 590080);     // 4 MB
    unsigned short* tbuf  = (unsigned short*)(ws + 4784384);    // 4 MB
    float*          L     = (float*)(ws + 8978688);             // 32 MB
    unsigned short* abuf  = (unsigned short*)(ws + 42533120);   // 16 MB
    unsigned short* Wf    = (unsigned short*)(ws + 59310336);   // 64 MB
    unsigned short* Xf    = (unsigned short*)(ws + 126419200);  // 32 MB
    unsigned short* W2f   = (unsigned short*)(ws + 159973632);  // 2 MB
    unsigned short* W1f   = (unsigned short*)(ws + 162070784);  // 256 KB

    hipMemsetAsync(cnt, 0, 256, stream);
    k_gather<<<dim3(B / 256), 256, 0, stream>>>(cid, cnt, idx);
    k_f2bf<<<dim3(256), 256, 0, stream>>>(z, zbf, B * LATENT / 4);
    k_repack_frag<<<dim3(4, 4, 1), 256, 0, stream>>>(W1, W1f, 128, HID, 0, 0, 0);
    k_repack_frag<<<dim3(32, 4, 1), 256, 0, stream>>>(W2, W2f, HID, HID, 0, 0, 0);
    k_repack_frag<<<dim3(32, 16, C), 256, 0, stream>>>(
        Wa, Wf, HID, NMAX, (size_t)HID * NMAX, 4194304, 1);
    k_repack_frag<<<dim3(128, 2, C), 256, 0, stream>>>(
        Xbuf, Xf, NMAX, D, (size_t)NMAX * D, 2097152, 2);
    k_mlp_mfma<<<dim3(B / 128, HID / 64), 256, 0, stream>>>(
        zbf, W1f, b1, W1 + (size_t)LATENT * HID, cid, h, LATENT);
    k_mlp_mfma<<<dim3(B / 128, HID / 64), 256, 0, stream>>>(
        h, W2f, b2, nullptr, cid, tbuf, HID);
    k_logits_mfma<<<dim3(B / 128, C, NMAX / 64), 256, 0, stream>>>(
        tbuf, Wf, ba, cnt, idx, L);
    k_softmax<<<dim3(B), 256, 0, stream>>>(L, abuf, cid);
    hipMemsetAsync(out, 0, (size_t)B * D * sizeof(float), stream);
    k_synth_mfma<<<dim3(B / 128, C, 32), 256, 0, stream>>>(
        abuf, Xf, cnt, idx, out);
}